// Round 3
// baseline (792.812 us; speedup 1.0000x reference)
//
#include <hip/hip_runtime.h>
#include <hip/hip_fp16.h>

typedef _Float16 half2_t __attribute__((ext_vector_type(2)));
typedef unsigned int u32;

// ---------------- problem dims ----------------
constexpr int Bn = 64, Sn = 256, Ln = 9;
constexpr int G4H = 1024;   // 4*H

// ---------------- workspace layout (bytes) ----------------
constexpr size_t XZ_OFF   = 0;                                  // [2][64][256][1024] f32
constexpr size_t XZ_BYTES = (size_t)2 * Bn * Sn * G4H * 4;      // 128 MB
constexpr size_t H_OFF    = XZ_OFF + XZ_BYTES;                  // [64][256][512] f32 (fwd|bwd)
constexpr size_t H_BYTES  = (size_t)Bn * Sn * 512 * 4;          // 32 MB
constexpr size_t UPK_OFF  = H_OFF + H_BYTES;                    // [2][128][1024] u32 (f16 pairs)
constexpr size_t UPK_BYTES= (size_t)2 * 128 * G4H * 4;          // 1 MB

// U split per gate-column: 128 f16-pairs = PV in VGPR + PL in LDS
constexpr int PV = 96;      // pairs held in VGPRs (192 regs for 2 cols)
constexpr int PL = 32;      // pairs held in LDS  (2*32*512*4 = 128 KB)

// ---------------- helpers ----------------
__device__ __forceinline__ float sigf(float x) {
  return __fdividef(1.0f, 1.0f + __expf(-x));
}
__device__ __forceinline__ float tanhf_fast(float x) {
  x = fminf(fmaxf(x, -15.0f), 15.0f);
  float e = __expf(-2.0f * x);
  return __fdividef(1.0f - e, 1.0f + e);
}

#if __has_builtin(__builtin_amdgcn_fdot2)
__device__ __forceinline__ float FDOT2(half2_t a, half2_t b, float c) {
  return __builtin_amdgcn_fdot2(a, b, c, false);
}
#else
__device__ __forceinline__ float FDOT2(half2_t a, half2_t b, float c) {
  return c + (float)a.x * (float)b.x + (float)a.y * (float)b.y;
}
#endif

__device__ __forceinline__ half2_t H2(u32 w) { return __builtin_bit_cast(half2_t, w); }

// ---------------- kernel 1: pack U (f32 -> f16 pair u32) ----------------
// upk[dir][kp][col]: pair (U[2kp][col], U[2kp+1][col])
__global__ void pack_u(const float* __restrict__ Uf, const float* __restrict__ Ub,
                       u32* __restrict__ upk) {
  int idx = blockIdx.x * 256 + threadIdx.x;      // [2][128][1024]
  if (idx >= 2 * 128 * 1024) return;
  int d  = idx >> 17;
  int kp = (idx >> 10) & 127;
  int j  = idx & 1023;
  const float* U = d ? Ub : Uf;
  _Float16 a = (_Float16)U[(size_t)(2 * kp) * 1024 + j];
  _Float16 b = (_Float16)U[(size_t)(2 * kp + 1) * 1024 + j];
  u32 pa = (u32)__builtin_bit_cast(unsigned short, a);
  u32 pb = (u32)__builtin_bit_cast(unsigned short, b);
  upk[idx] = pa | (pb << 16);
}

// ---------------- kernel 2: xz = gather(emb) @ [Wf|Wb] + bias ----------------
// M=16384 (b*256+s), N=2048 (dir*1024+j), K=256. Tile 64x128x32, 256 threads.
__global__ __launch_bounds__(256, 4)
void xz_gemm(const int* __restrict__ tok, const float* __restrict__ emb,
             const float* __restrict__ Wf, const float* __restrict__ biasf,
             const float* __restrict__ Wb, const float* __restrict__ biasb,
             float* __restrict__ xz) {
  __shared__ float As[32][64];
  __shared__ float Bs[32][128];
  __shared__ int toks[64];
  const int tid = threadIdx.x;
  const int mt = blockIdx.x, nt = blockIdx.y;
  const int d = nt >> 3;
  const float* W    = d ? Wb : Wf;
  const float* bias = d ? biasb : biasf;
  const int n0 = (nt & 7) * 128;
  const int r0 = mt * 64;
  if (tid < 64) toks[tid] = tok[r0 + tid];
  __syncthreads();
  const int tr = tid >> 4, tc = tid & 15;
  float acc[4][8];
#pragma unroll
  for (int j = 0; j < 8; ++j) {
    float bv = bias[n0 + tc * 8 + j];
#pragma unroll
    for (int i = 0; i < 4; ++i) acc[i][j] = bv;
  }
  const int ai = tid >> 2, kq = tid & 3;
  const int kb = tid >> 3, fb = tid & 7;
  for (int k0 = 0; k0 < 256; k0 += 32) {
    const float* ar = emb + (size_t)toks[ai] * 256 + k0 + kq * 8;
    float4 a0 = *(const float4*)ar;
    float4 a1 = *(const float4*)(ar + 4);
    As[kq * 8 + 0][ai] = a0.x; As[kq * 8 + 1][ai] = a0.y;
    As[kq * 8 + 2][ai] = a0.z; As[kq * 8 + 3][ai] = a0.w;
    As[kq * 8 + 4][ai] = a1.x; As[kq * 8 + 5][ai] = a1.y;
    As[kq * 8 + 6][ai] = a1.z; As[kq * 8 + 7][ai] = a1.w;
    const float* wr = W + (size_t)(k0 + kb) * 1024 + n0;
#pragma unroll
    for (int q = 0; q < 4; ++q)
      *(float4*)&Bs[kb][(fb + 8 * q) * 4] = *(const float4*)(wr + (fb + 8 * q) * 4);
    __syncthreads();
#pragma unroll
    for (int kk = 0; kk < 32; ++kk) {
      float4 a4 = *(const float4*)&As[kk][tr * 4];
      float4 b0 = *(const float4*)&Bs[kk][tc * 8];
      float4 b1 = *(const float4*)&Bs[kk][tc * 8 + 4];
      float av[4] = {a4.x, a4.y, a4.z, a4.w};
      float bv[8] = {b0.x, b0.y, b0.z, b0.w, b1.x, b1.y, b1.z, b1.w};
#pragma unroll
      for (int i = 0; i < 4; ++i)
#pragma unroll
        for (int j = 0; j < 8; ++j) acc[i][j] += av[i] * bv[j];
    }
    __syncthreads();
  }
#pragma unroll
  for (int i = 0; i < 4; ++i) {
    int r = r0 + tr * 4 + i;
    int bb_ = r >> 8, s = r & 255;
    float* dst = xz + ((size_t)(d * 64 + bb_) * 256 + s) * 1024 + n0 + tc * 8;
    float4 o0 = {acc[i][0], acc[i][1], acc[i][2], acc[i][3]};
    float4 o1 = {acc[i][4], acc[i][5], acc[i][6], acc[i][7]};
    *(float4*)dst = o0;
    *(float4*)(dst + 4) = o1;
  }
}

// ---------------- kernel 3: LSTM recurrence, ONE block per sequence ----------------
// 128 blocks x 512 threads. block = seq = dir*64 + b. Each thread owns gate
// columns colA=tid (i/f) and colB=tid+512 (g/o). U column = 128 f16-pairs:
// pairs [0,PV) pinned in VGPRs (asm keep-alive prevents remat), pairs
// [PV,128) in LDS. h broadcast via LDS. 2 syncthreads per step, no
// inter-block communication.
__global__ __launch_bounds__(512, 2)
void lstm_seq(const float* __restrict__ xz, const u32* __restrict__ upk,
              float* __restrict__ h_out) {
  const int seq = blockIdx.x;     // 0..127
  const int dir = seq >> 6;
  const int tid = threadIdx.x;
  const int colA = tid;
  const int colB = tid + 512;

  __shared__ uint4 ul[2 * (PL / 4) * 512];     // [colSel][q][tid], 128 KB
  __shared__ float zbuf[1024];                  // 4 KB
  __shared__ __align__(16) u32 h2[128];         // 128 packed f16-pairs of h

  const u32* ubase = upk + (size_t)dir * 131072;

  // --- load U: VGPR part (pairs 0..PV-1), pinned live via asm ---
  half2_t uA[PV], uB[PV];
#pragma unroll
  for (int kp = 0; kp < PV; ++kp) {
    uA[kp] = H2(ubase[(size_t)kp * 1024 + colA]);
    uB[kp] = H2(ubase[(size_t)kp * 1024 + colB]);
  }
#pragma unroll
  for (int kp = 0; kp < PV; ++kp) {
    asm volatile("" : "+v"(uA[kp]));
    asm volatile("" : "+v"(uB[kp]));
  }
  // --- load U: LDS part (pairs PV..127), contiguous uint4 per thread ---
#pragma unroll
  for (int q = 0; q < PL / 4; ++q) {
    uint4 va, vb;
    va.x = ubase[(size_t)(PV + 4 * q + 0) * 1024 + colA];
    va.y = ubase[(size_t)(PV + 4 * q + 1) * 1024 + colA];
    va.z = ubase[(size_t)(PV + 4 * q + 2) * 1024 + colA];
    va.w = ubase[(size_t)(PV + 4 * q + 3) * 1024 + colA];
    vb.x = ubase[(size_t)(PV + 4 * q + 0) * 1024 + colB];
    vb.y = ubase[(size_t)(PV + 4 * q + 1) * 1024 + colB];
    vb.z = ubase[(size_t)(PV + 4 * q + 2) * 1024 + colB];
    vb.w = ubase[(size_t)(PV + 4 * q + 3) * 1024 + colB];
    ul[q * 512 + tid] = va;
    ul[(PL / 4 + q) * 512 + tid] = vb;
  }
  if (tid < 128) h2[tid] = 0u;
  float c = 0.0f;

  const float* xzp = xz + (size_t)seq * 256 * 1024;
  float* hop = h_out + (size_t)(seq & 63) * 256 * 512 + dir * 256 + tid;  // deref only tid<256
  __syncthreads();

  // prefetch step 0
  float xA = xzp[(size_t)(dir ? 255 : 0) * 1024 + colA];
  float xB = xzp[(size_t)(dir ? 255 : 0) * 1024 + colB];

  for (int t = 0; t < 256; ++t) {
    // prefetch next step's xz (clamped on last iter; result unused then)
    const int snext = (t < 255) ? (dir ? (254 - t) : (t + 1)) : (dir ? 255 : 0);
    float nA = xzp[(size_t)snext * 1024 + colA];
    float nB = xzp[(size_t)snext * 1024 + colB];

    float accA = xA, accB = xB;
    // VGPR-resident U: pairs 0..PV-1, h broadcast from LDS in uint4 chunks
#pragma unroll
    for (int q = 0; q < PV / 4; ++q) {
      uint4 hh = *(const uint4*)&h2[4 * q];
      accA = FDOT2(H2(hh.x), uA[4 * q + 0], accA);
      accA = FDOT2(H2(hh.y), uA[4 * q + 1], accA);
      accA = FDOT2(H2(hh.z), uA[4 * q + 2], accA);
      accA = FDOT2(H2(hh.w), uA[4 * q + 3], accA);
      accB = FDOT2(H2(hh.x), uB[4 * q + 0], accB);
      accB = FDOT2(H2(hh.y), uB[4 * q + 1], accB);
      accB = FDOT2(H2(hh.z), uB[4 * q + 2], accB);
      accB = FDOT2(H2(hh.w), uB[4 * q + 3], accB);
    }
    // LDS-resident U: pairs PV..127
#pragma unroll
    for (int q = 0; q < PL / 4; ++q) {
      uint4 hh = *(const uint4*)&h2[PV + 4 * q];
      uint4 va = ul[q * 512 + tid];
      uint4 vb = ul[(PL / 4 + q) * 512 + tid];
      accA = FDOT2(H2(hh.x), H2(va.x), accA);
      accA = FDOT2(H2(hh.y), H2(va.y), accA);
      accA = FDOT2(H2(hh.z), H2(va.z), accA);
      accA = FDOT2(H2(hh.w), H2(va.w), accA);
      accB = FDOT2(H2(hh.x), H2(vb.x), accB);
      accB = FDOT2(H2(hh.y), H2(vb.y), accB);
      accB = FDOT2(H2(hh.z), H2(vb.z), accB);
      accB = FDOT2(H2(hh.w), H2(vb.w), accB);
    }
    zbuf[colA] = accA;
    zbuf[colB] = accB;
    __syncthreads();

    const int s = dir ? (255 - t) : t;
    if (tid < 256) {
      float zi = zbuf[tid], zf = zbuf[tid + 256], zg = zbuf[tid + 512], zo = zbuf[tid + 768];
      c = sigf(zf) * c + sigf(zi) * tanhf_fast(zg);
      float h = sigf(zo) * tanhf_fast(c);
      hop[(size_t)s * 512] = h;
      ((_Float16*)h2)[tid] = (_Float16)h;
    }
    __syncthreads();
    xA = nA; xB = nB;
  }
}

// ---------------- kernel 4: logits = h @ W_dense + b_dense ----------------
__global__ __launch_bounds__(256, 4)
void logits_k(const float* __restrict__ h_out, const float* __restrict__ Wd,
              const float* __restrict__ bd, float* __restrict__ out) {
  __shared__ float Ws[512 * 9];
  __shared__ float bs[16];
  const int tid = threadIdx.x;
  for (int i = tid; i < 4608; i += 256) Ws[i] = Wd[i];
  if (tid < 9) bs[tid] = bd[tid];
  __syncthreads();
  const int w = tid >> 6, lane = tid & 63;
  const int r0 = blockIdx.x * 16 + w * 4;
  for (int rr = 0; rr < 4; ++rr) {
    const int r = r0 + rr;
    const float* hp = h_out + (size_t)r * 512 + lane * 8;
    float4 h0 = *(const float4*)hp;
    float4 h1 = *(const float4*)(hp + 4);
    float hv[8] = {h0.x, h0.y, h0.z, h0.w, h1.x, h1.y, h1.z, h1.w};
    float outv = 0.0f;
#pragma unroll
    for (int l = 0; l < 9; ++l) {
      float p = 0.0f;
#pragma unroll
      for (int uu = 0; uu < 8; ++uu) p += hv[uu] * Ws[(lane * 8 + uu) * 9 + l];
      for (int off = 32; off; off >>= 1) p += __shfl_xor(p, off, 64);
      if (lane == l) outv = p;
    }
    if (lane < 9) out[(size_t)r * 9 + lane] = outv + bs[lane];
  }
}

// ---------------- kernel 5: CRF log-likelihood ----------------
__global__ void crf_k(const float* __restrict__ logits, const int* __restrict__ label,
                      const int* __restrict__ mask, const float* __restrict__ trans,
                      float* __restrict__ out_ll, float* __restrict__ out_trans) {
  const int b = blockIdx.x;
  const int lane = threadIdx.x;
  int cnt = 0;
#pragma unroll
  for (int q = 0; q < 4; ++q) cnt += (mask[b * 256 + lane + q * 64] != 0) ? 1 : 0;
  for (int off = 32; off; off >>= 1) cnt += __shfl_xor(cnt, off, 64);
  const int len = cnt;
  float un = 0.0f;
#pragma unroll
  for (int q = 0; q < 4; ++q) {
    int s = lane + q * 64;
    if (s < len) un += logits[((size_t)b * 256 + s) * 9 + label[b * 256 + s]];
  }
  for (int off = 32; off; off >>= 1) un += __shfl_xor(un, off, 64);
  float bin = 0.0f;
#pragma unroll
  for (int q = 0; q < 4; ++q) {
    int s = lane + q * 64;
    if (s < 255 && s < len - 1)
      bin += trans[label[b * 256 + s] * 9 + label[b * 256 + s + 1]];
  }
  for (int off = 32; off; off >>= 1) bin += __shfl_xor(bin, off, 64);
  float alpha = (lane < 9) ? logits[((size_t)b * 256) * 9 + lane] : -INFINITY;
  float tcol[9];
  if (lane < 9) {
#pragma unroll
    for (int i = 0; i < 9; ++i) tcol[i] = trans[i * 9 + lane];
  }
  for (int t = 1; t < 256; ++t) {
    float a[9];
#pragma unroll
    for (int i = 0; i < 9; ++i) a[i] = __shfl(alpha, i, 64);
    if (lane < 9) {
      float mx = a[0] + tcol[0];
#pragma unroll
      for (int i = 1; i < 9; ++i) mx = fmaxf(mx, a[i] + tcol[i]);
      float ssum = 0.0f;
#pragma unroll
      for (int i = 0; i < 9; ++i) ssum += __expf(a[i] + tcol[i] - mx);
      float nw = mx + __logf(ssum) + logits[((size_t)b * 256 + t) * 9 + lane];
      if (t < len) alpha = nw;
    }
  }
  float mx = alpha;
  for (int off = 32; off; off >>= 1) mx = fmaxf(mx, __shfl_xor(mx, off, 64));
  float e = __expf(alpha - mx);
  for (int off = 32; off; off >>= 1) e += __shfl_xor(e, off, 64);
  if (lane == 0) out_ll[b] = un + bin - (mx + __logf(e));
  if (b == 0) {
    for (int i = lane; i < 81; i += 64) out_trans[i] = trans[i];
  }
}

// ---------------- launch ----------------
extern "C" void kernel_launch(void* const* d_in, const int* in_sizes, int n_in,
                              void* d_out, int out_size, void* d_ws, size_t ws_size,
                              hipStream_t stream) {
  (void)in_sizes; (void)n_in; (void)out_size; (void)ws_size;
  const int*   inputs = (const int*)d_in[0];
  const int*   amask  = (const int*)d_in[1];
  const int*   label  = (const int*)d_in[2];
  const float* emb    = (const float*)d_in[3];
  const float* Wf     = (const float*)d_in[4];
  const float* Uf     = (const float*)d_in[5];
  const float* bf     = (const float*)d_in[6];
  const float* Wb     = (const float*)d_in[7];
  const float* Ub     = (const float*)d_in[8];
  const float* bb     = (const float*)d_in[9];
  const float* Wd     = (const float*)d_in[10];
  const float* bd     = (const float*)d_in[11];
  const float* trans  = (const float*)d_in[12];

  char* ws = (char*)d_ws;
  float* xz    = (float*)(ws + XZ_OFF);
  float* h_out = (float*)(ws + H_OFF);
  u32*   upk   = (u32*)(ws + UPK_OFF);

  float* out      = (float*)d_out;
  float* out_ll   = out + (size_t)Bn * Sn * Ln;        // 147456
  float* out_tr   = out_ll + Bn;                       // 147520

  pack_u<<<1024, 256, 0, stream>>>(Uf, Ub, upk);
  xz_gemm<<<dim3(256, 16), 256, 0, stream>>>(inputs, emb, Wf, bf, Wb, bb, xz);
  lstm_seq<<<128, 512, 0, stream>>>(xz, upk, h_out);
  logits_k<<<1024, 256, 0, stream>>>(h_out, Wd, bd, out);
  crf_k<<<64, 64, 0, stream>>>(out, label, amask, trans, out_ll, out_tr);
}

// Round 4
// 762.141 us; speedup vs baseline: 1.0402x; 1.0402x over previous
//
#include <hip/hip_runtime.h>
#include <hip/hip_fp16.h>

typedef _Float16 half2_t __attribute__((ext_vector_type(2)));
typedef unsigned int u32;

// ---------------- problem dims ----------------
constexpr int Bn = 64, Sn = 256, Ln = 9;
constexpr int G4H = 1024;   // 4*H

// ---------------- workspace layout (bytes) ----------------
constexpr size_t XZ_OFF   = 0;                                  // [2][64][256][1024] f32
constexpr size_t XZ_BYTES = (size_t)2 * Bn * Sn * G4H * 4;      // 128 MB
constexpr size_t H_OFF    = XZ_OFF + XZ_BYTES;                  // [64][256][512] f32 (fwd|bwd)
constexpr size_t H_BYTES  = (size_t)Bn * Sn * 512 * 4;          // 32 MB
constexpr size_t UPK_OFF  = H_OFF + H_BYTES;                    // [2][128][1024] u32 (f16 pairs)
constexpr size_t UPK_BYTES= (size_t)2 * 128 * G4H * 4;          // 1 MB

// ---------------- helpers ----------------
__device__ __forceinline__ float sigf(float x) {
  return __fdividef(1.0f, 1.0f + __expf(-x));
}
__device__ __forceinline__ float tanhf_fast(float x) {
  x = fminf(fmaxf(x, -15.0f), 15.0f);
  float e = __expf(-2.0f * x);
  return __fdividef(1.0f - e, 1.0f + e);
}

#if __has_builtin(__builtin_amdgcn_fdot2)
__device__ __forceinline__ float FDOT2(half2_t a, half2_t b, float c) {
  return __builtin_amdgcn_fdot2(a, b, c, false);
}
#else
__device__ __forceinline__ float FDOT2(half2_t a, half2_t b, float c) {
  return c + (float)a.x * (float)b.x + (float)a.y * (float)b.y;
}
#endif

__device__ __forceinline__ half2_t H2(u32 w) { return __builtin_bit_cast(half2_t, w); }

// h2 granule swizzle: granule g (4 u32 = 8 h-values) stored at granule slot swz(g).
// Within each 8-granule block (one kb slice), rotate by 2*kb so concurrent reads
// from the 4 kb groups hit disjoint bank-groups.
__device__ __forceinline__ int swz_g(int g) {
  return (g & 24) | ((g + 2 * (g >> 3)) & 7);
}

// ---------------- kernel 1: pack U (f32 -> f16 pair u32) ----------------
// upk[dir][kp][col]: pair (U[2kp][col], U[2kp+1][col])
__global__ void pack_u(const float* __restrict__ Uf, const float* __restrict__ Ub,
                       u32* __restrict__ upk) {
  int idx = blockIdx.x * 256 + threadIdx.x;      // [2][128][1024]
  if (idx >= 2 * 128 * 1024) return;
  int d  = idx >> 17;
  int kp = (idx >> 10) & 127;
  int j  = idx & 1023;
  const float* U = d ? Ub : Uf;
  _Float16 a = (_Float16)U[(size_t)(2 * kp) * 1024 + j];
  _Float16 b = (_Float16)U[(size_t)(2 * kp + 1) * 1024 + j];
  u32 pa = (u32)__builtin_bit_cast(unsigned short, a);
  u32 pb = (u32)__builtin_bit_cast(unsigned short, b);
  upk[idx] = pa | (pb << 16);
}

// ---------------- kernel 2: xz = gather(emb) @ [Wf|Wb] + bias ----------------
__global__ __launch_bounds__(256, 4)
void xz_gemm(const int* __restrict__ tok, const float* __restrict__ emb,
             const float* __restrict__ Wf, const float* __restrict__ biasf,
             const float* __restrict__ Wb, const float* __restrict__ biasb,
             float* __restrict__ xz) {
  __shared__ float As[32][64];
  __shared__ float Bs[32][128];
  __shared__ int toks[64];
  const int tid = threadIdx.x;
  const int mt = blockIdx.x, nt = blockIdx.y;
  const int d = nt >> 3;
  const float* W    = d ? Wb : Wf;
  const float* bias = d ? biasb : biasf;
  const int n0 = (nt & 7) * 128;
  const int r0 = mt * 64;
  if (tid < 64) toks[tid] = tok[r0 + tid];
  __syncthreads();
  const int tr = tid >> 4, tc = tid & 15;
  float acc[4][8];
#pragma unroll
  for (int j = 0; j < 8; ++j) {
    float bv = bias[n0 + tc * 8 + j];
#pragma unroll
    for (int i = 0; i < 4; ++i) acc[i][j] = bv;
  }
  const int ai = tid >> 2, kq = tid & 3;
  const int kb = tid >> 3, fb = tid & 7;
  for (int k0 = 0; k0 < 256; k0 += 32) {
    const float* ar = emb + (size_t)toks[ai] * 256 + k0 + kq * 8;
    float4 a0 = *(const float4*)ar;
    float4 a1 = *(const float4*)(ar + 4);
    As[kq * 8 + 0][ai] = a0.x; As[kq * 8 + 1][ai] = a0.y;
    As[kq * 8 + 2][ai] = a0.z; As[kq * 8 + 3][ai] = a0.w;
    As[kq * 8 + 4][ai] = a1.x; As[kq * 8 + 5][ai] = a1.y;
    As[kq * 8 + 6][ai] = a1.z; As[kq * 8 + 7][ai] = a1.w;
    const float* wr = W + (size_t)(k0 + kb) * 1024 + n0;
#pragma unroll
    for (int q = 0; q < 4; ++q)
      *(float4*)&Bs[kb][(fb + 8 * q) * 4] = *(const float4*)(wr + (fb + 8 * q) * 4);
    __syncthreads();
#pragma unroll
    for (int kk = 0; kk < 32; ++kk) {
      float4 a4 = *(const float4*)&As[kk][tr * 4];
      float4 b0 = *(const float4*)&Bs[kk][tc * 8];
      float4 b1 = *(const float4*)&Bs[kk][tc * 8 + 4];
      float av[4] = {a4.x, a4.y, a4.z, a4.w};
      float bv[8] = {b0.x, b0.y, b0.z, b0.w, b1.x, b1.y, b1.z, b1.w};
#pragma unroll
      for (int i = 0; i < 4; ++i)
#pragma unroll
        for (int j = 0; j < 8; ++j) acc[i][j] += av[i] * bv[j];
    }
    __syncthreads();
  }
#pragma unroll
  for (int i = 0; i < 4; ++i) {
    int r = r0 + tr * 4 + i;
    int bb_ = r >> 8, s = r & 255;
    float* dst = xz + ((size_t)(d * 64 + bb_) * 256 + s) * 1024 + n0 + tc * 8;
    float4 o0 = {acc[i][0], acc[i][1], acc[i][2], acc[i][3]};
    float4 o1 = {acc[i][4], acc[i][5], acc[i][6], acc[i][7]};
    *(float4*)dst = o0;
    *(float4*)(dst + 4) = o1;
  }
}

// ---------------- kernel 3: LSTM recurrence, k-split design ----------------
// 128 blocks x 512 threads, block = seq = dir*64 + b. Lane decomposition:
//   kb = lane & 3  : owns k-pairs [32kb, 32kb+32)   (k-split over 4 lanes)
//   cb = lane >> 2 : with wave w, owns cols c0 = w*128 + cb*8 .. c0+7
// Per thread U tile = 32 pairs x 8 cols = 256 entries: cols 0..5 in VGPR
// (192 regs), cols 6,7 in LDS (128 KB). Per step: 8 hh b128 reads (own
// k-slice of h, granule-swizzled vs kb), 16 ul b128 reads, 256 fdot2,
// 2-hop shfl_xor reduce over kb, gates on tid<256. Two barriers/step.
__global__ __launch_bounds__(512)
__attribute__((amdgpu_waves_per_eu(2, 2)))
void lstm_seq(const float* __restrict__ xz, const u32* __restrict__ upk,
              float* __restrict__ h_out) {
  const int seq = blockIdx.x;     // 0..127
  const int dir = seq >> 6;
  const int tid = threadIdx.x;
  const int w    = tid >> 6;
  const int lane = tid & 63;
  const int kb   = lane & 3;
  const int cb   = lane >> 2;
  const int c0   = w * 128 + cb * 8;

  __shared__ uint4 ul[16][512];                 // LDS U cols 6,7: [cl*8+s][tid], 128 KB
  __shared__ float zbuf[1024];                  // 4 KB
  __shared__ __align__(16) u32 h2[128];         // swizzled h granules, 512 B

  const u32* ub = upk + (size_t)dir * 131072;

  // --- load U: VGPR cols j=0..5, pairs 32kb+q ---
  half2_t uu[6][32];
#pragma unroll
  for (int j = 0; j < 6; ++j)
#pragma unroll
    for (int q = 0; q < 32; ++q)
      uu[j][q] = H2(ub[(size_t)(32 * kb + q) * 1024 + (c0 + j)]);
#pragma unroll
  for (int j = 0; j < 6; ++j)
#pragma unroll
    for (int q = 0; q < 32; ++q)
      asm volatile("" : "+v"(uu[j][q]));

  // --- load U: LDS cols 6,7 ---
#pragma unroll
  for (int cl = 0; cl < 2; ++cl)
#pragma unroll
    for (int s = 0; s < 8; ++s) {
      uint4 v;
      v.x = ub[(size_t)(32 * kb + 4 * s + 0) * 1024 + (c0 + 6 + cl)];
      v.y = ub[(size_t)(32 * kb + 4 * s + 1) * 1024 + (c0 + 6 + cl)];
      v.z = ub[(size_t)(32 * kb + 4 * s + 2) * 1024 + (c0 + 6 + cl)];
      v.w = ub[(size_t)(32 * kb + 4 * s + 3) * 1024 + (c0 + 6 + cl)];
      ul[cl * 8 + s][tid] = v;
    }
  if (tid < 128) h2[tid] = 0u;

  // --- hh read addresses (loop-invariant, swizzled) ---
  const char* h2b = (const char*)h2;
  int hhoff[8];
#pragma unroll
  for (int s = 0; s < 8; ++s)
    hhoff[s] = 16 * ((kb << 3) | ((s + 2 * kb) & 7));

  // gate-phase constants (tid<256): write h element tid into swizzled h2
  float c = 0.0f;
  char* hwp = (char*)h2 + (swz_g(tid >> 3) * 16 + (tid & 7) * 2);
  float* hop = h_out + (size_t)(seq & 63) * 256 * 512 + dir * 256 + tid;  // deref tid<256

  const float* xzp = xz + (size_t)seq * 256 * 1024 + c0;
  __syncthreads();

  // prefetch step 0 xz
  float4 xc0 = *(const float4*)(xzp + (size_t)(dir ? 255 : 0) * 1024);
  float4 xc1 = *(const float4*)(xzp + (size_t)(dir ? 255 : 0) * 1024 + 4);

  for (int t = 0; t < 256; ++t) {
    const int scur = dir ? (255 - t) : t;
    const int snext = (t < 255) ? (dir ? (254 - t) : (t + 1)) : (dir ? 255 : 0);
    float4 nx0 = *(const float4*)(xzp + (size_t)snext * 1024);
    float4 nx1 = *(const float4*)(xzp + (size_t)snext * 1024 + 4);

    float acc[8] = {0.f, 0.f, 0.f, 0.f, 0.f, 0.f, 0.f, 0.f};
#pragma unroll
    for (int s = 0; s < 8; ++s) {
      uint4 hh = *(const uint4*)(h2b + hhoff[s]);
      uint4 va = ul[s][tid];
      uint4 vb = ul[8 + s][tid];
#pragma unroll
      for (int j = 0; j < 6; ++j) {
        acc[j] = FDOT2(H2(hh.x), uu[j][4 * s + 0], acc[j]);
        acc[j] = FDOT2(H2(hh.y), uu[j][4 * s + 1], acc[j]);
        acc[j] = FDOT2(H2(hh.z), uu[j][4 * s + 2], acc[j]);
        acc[j] = FDOT2(H2(hh.w), uu[j][4 * s + 3], acc[j]);
      }
      acc[6] = FDOT2(H2(hh.x), H2(va.x), acc[6]);
      acc[6] = FDOT2(H2(hh.y), H2(va.y), acc[6]);
      acc[6] = FDOT2(H2(hh.z), H2(va.z), acc[6]);
      acc[6] = FDOT2(H2(hh.w), H2(va.w), acc[6]);
      acc[7] = FDOT2(H2(hh.x), H2(vb.x), acc[7]);
      acc[7] = FDOT2(H2(hh.y), H2(vb.y), acc[7]);
      acc[7] = FDOT2(H2(hh.z), H2(vb.z), acc[7]);
      acc[7] = FDOT2(H2(hh.w), H2(vb.w), acc[7]);
    }
    // reduce partials over kb group (lanes xor 1, 2)
#pragma unroll
    for (int j = 0; j < 8; ++j) {
      acc[j] += __shfl_xor(acc[j], 1, 64);
      acc[j] += __shfl_xor(acc[j], 2, 64);
    }
    if (kb == 0) {
      float4 z0 = {acc[0] + xc0.x, acc[1] + xc0.y, acc[2] + xc0.z, acc[3] + xc0.w};
      float4 z1 = {acc[4] + xc1.x, acc[5] + xc1.y, acc[6] + xc1.z, acc[7] + xc1.w};
      *(float4*)&zbuf[c0] = z0;
      *(float4*)&zbuf[c0 + 4] = z1;
    }
    __syncthreads();

    if (tid < 256) {
      float zi = zbuf[tid], zf = zbuf[tid + 256], zg = zbuf[tid + 512], zo = zbuf[tid + 768];
      c = sigf(zf) * c + sigf(zi) * tanhf_fast(zg);
      float h = sigf(zo) * tanhf_fast(c);
      hop[(size_t)scur * 512] = h;
      *(_Float16*)hwp = (_Float16)h;
    }
    __syncthreads();
    xc0 = nx0; xc1 = nx1;
  }
}

// ---------------- kernel 4: logits = h @ W_dense + b_dense ----------------
__global__ __launch_bounds__(256, 4)
void logits_k(const float* __restrict__ h_out, const float* __restrict__ Wd,
              const float* __restrict__ bd, float* __restrict__ out) {
  __shared__ float Ws[512 * 9];
  __shared__ float bs[16];
  const int tid = threadIdx.x;
  for (int i = tid; i < 4608; i += 256) Ws[i] = Wd[i];
  if (tid < 9) bs[tid] = bd[tid];
  __syncthreads();
  const int w = tid >> 6, lane = tid & 63;
  const int r0 = blockIdx.x * 16 + w * 4;
  for (int rr = 0; rr < 4; ++rr) {
    const int r = r0 + rr;
    const float* hp = h_out + (size_t)r * 512 + lane * 8;
    float4 h0 = *(const float4*)hp;
    float4 h1 = *(const float4*)(hp + 4);
    float hv[8] = {h0.x, h0.y, h0.z, h0.w, h1.x, h1.y, h1.z, h1.w};
    float outv = 0.0f;
#pragma unroll
    for (int l = 0; l < 9; ++l) {
      float p = 0.0f;
#pragma unroll
      for (int uu = 0; uu < 8; ++uu) p += hv[uu] * Ws[(lane * 8 + uu) * 9 + l];
      for (int off = 32; off; off >>= 1) p += __shfl_xor(p, off, 64);
      if (lane == l) outv = p;
    }
    if (lane < 9) out[(size_t)r * 9 + lane] = outv + bs[lane];
  }
}

// ---------------- kernel 5: CRF log-likelihood ----------------
__global__ void crf_k(const float* __restrict__ logits, const int* __restrict__ label,
                      const int* __restrict__ mask, const float* __restrict__ trans,
                      float* __restrict__ out_ll, float* __restrict__ out_trans) {
  const int b = blockIdx.x;
  const int lane = threadIdx.x;
  int cnt = 0;
#pragma unroll
  for (int q = 0; q < 4; ++q) cnt += (mask[b * 256 + lane + q * 64] != 0) ? 1 : 0;
  for (int off = 32; off; off >>= 1) cnt += __shfl_xor(cnt, off, 64);
  const int len = cnt;
  float un = 0.0f;
#pragma unroll
  for (int q = 0; q < 4; ++q) {
    int s = lane + q * 64;
    if (s < len) un += logits[((size_t)b * 256 + s) * 9 + label[b * 256 + s]];
  }
  for (int off = 32; off; off >>= 1) un += __shfl_xor(un, off, 64);
  float bin = 0.0f;
#pragma unroll
  for (int q = 0; q < 4; ++q) {
    int s = lane + q * 64;
    if (s < 255 && s < len - 1)
      bin += trans[label[b * 256 + s] * 9 + label[b * 256 + s + 1]];
  }
  for (int off = 32; off; off >>= 1) bin += __shfl_xor(bin, off, 64);
  float alpha = (lane < 9) ? logits[((size_t)b * 256) * 9 + lane] : -INFINITY;
  float tcol[9];
  if (lane < 9) {
#pragma unroll
    for (int i = 0; i < 9; ++i) tcol[i] = trans[i * 9 + lane];
  }
  for (int t = 1; t < 256; ++t) {
    float a[9];
#pragma unroll
    for (int i = 0; i < 9; ++i) a[i] = __shfl(alpha, i, 64);
    if (lane < 9) {
      float mx = a[0] + tcol[0];
#pragma unroll
      for (int i = 1; i < 9; ++i) mx = fmaxf(mx, a[i] + tcol[i]);
      float ssum = 0.0f;
#pragma unroll
      for (int i = 0; i < 9; ++i) ssum += __expf(a[i] + tcol[i] - mx);
      float nw = mx + __logf(ssum) + logits[((size_t)b * 256 + t) * 9 + lane];
      if (t < len) alpha = nw;
    }
  }
  float mx = alpha;
  for (int off = 32; off; off >>= 1) mx = fmaxf(mx, __shfl_xor(mx, off, 64));
  float e = __expf(alpha - mx);
  for (int off = 32; off; off >>= 1) e += __shfl_xor(e, off, 64);
  if (lane == 0) out_ll[b] = un + bin - (mx + __logf(e));
  if (b == 0) {
    for (int i = lane; i < 81; i += 64) out_trans[i] = trans[i];
  }
}

// ---------------- launch ----------------
extern "C" void kernel_launch(void* const* d_in, const int* in_sizes, int n_in,
                              void* d_out, int out_size, void* d_ws, size_t ws_size,
                              hipStream_t stream) {
  (void)in_sizes; (void)n_in; (void)out_size; (void)ws_size;
  const int*   inputs = (const int*)d_in[0];
  const int*   amask  = (const int*)d_in[1];
  const int*   label  = (const int*)d_in[2];
  const float* emb    = (const float*)d_in[3];
  const float* Wf     = (const float*)d_in[4];
  const float* Uf     = (const float*)d_in[5];
  const float* bf     = (const float*)d_in[6];
  const float* Wb     = (const float*)d_in[7];
  const float* Ub     = (const float*)d_in[8];
  const float* bb     = (const float*)d_in[9];
  const float* Wd     = (const float*)d_in[10];
  const float* bd     = (const float*)d_in[11];
  const float* trans  = (const float*)d_in[12];

  char* ws = (char*)d_ws;
  float* xz    = (float*)(ws + XZ_OFF);
  float* h_out = (float*)(ws + H_OFF);
  u32*   upk   = (u32*)(ws + UPK_OFF);

  float* out      = (float*)d_out;
  float* out_ll   = out + (size_t)Bn * Sn * Ln;        // 147456
  float* out_tr   = out_ll + Bn;                       // 147520

  pack_u<<<1024, 256, 0, stream>>>(Uf, Ub, upk);
  xz_gemm<<<dim3(256, 16), 256, 0, stream>>>(inputs, emb, Wf, bf, Wb, bb, xz);
  lstm_seq<<<128, 512, 0, stream>>>(xz, upk, h_out);
  logits_k<<<1024, 256, 0, stream>>>(h_out, Wd, bd, out);
  crf_k<<<64, 64, 0, stream>>>(out, label, amask, trans, out_ll, out_tr);
}